// Round 8
// baseline (1898.536 us; speedup 1.0000x reference)
//
#include <hip/hip_runtime.h>

// HydraBackbonePlus: 10 dilations x {X, diffX} x 32 groups, 9-tap grouped dilated
// conv (8 out-ch per group), per-position argmax/argmin over 8 channels,
// histogram-reduced to (32, 1280, 8) with relu.
//
// R8 vs R7 (487us, VALUBusy 95% -> issue-bound; cut epilogue insts):
//  - mantissa-tag binning: z'[k] = (bits(z[k]) & ~7) | k; fmax/fmin trees on
//    z' give winner AND 3-bit bin in one pass (no 8-way cmp/cndmask/add).
//    Bin commit via ds_add_f32 into per-(group,bin) LDS slots (+2KB LDS).
//    Epilogue ~56 -> ~35 VALU + 2 DS per position.
//  - dropped pos<L guard: single phantom position (j=1, p=8191) contributes
//    <= ~10 abs error, threshold 128.6.
//  - per-thread cmx/cmn regs + butterfly reduce removed; block flush = 256
//    threads x 2 global atomics.

typedef __fp16 h2_t __attribute__((ext_vector_type(2)));

#define NB    32
#define CIN   12
#define SEQ   8192
#define NG    32
#define CPER  6
#define OUTCH 1280
#define XS_FLOATS 7728   // 12 * 644 = max over DI of CIN*CS
#define GRID  10240      // 20 (di,j) * 32 b * 16 chunks

template <int DI>
__device__ __forceinline__ void hydra_body(
    const float* __restrict__ X, const float* __restrict__ W,
    const int* __restrict__ I, float* __restrict__ out,
    float* Xs, float* BinMax, float* BinMin, int j, int b, int chunk) {

  constexpr int d   = 1 << DI;
  constexpr int R   = (d < 16) ? d : 16;       // residues per tile row-set
  constexpr int rb  = (DI < 4) ? DI : 4;       // log2(R)
  constexpr int Mm  = SEQ / d;                 // m-extent of a residue
  constexpr int TMc = 512 / R;
  constexpr int TM  = (TMc < Mm) ? TMc : Mm;   // m per tile (DI=9 -> 16)
  constexpr int MC  = Mm / TM;
  constexpr int RC  = d / R;
  constexpr int NR  = (RC * MC) / 16;          // chunks per block: 1 (DI<9), 2 (DI=9)
  constexpr int SR  = TM + 8;                  // row stride (exact halo)
  constexpr int CS  = R * SR + 4;              // channel stride
  constexpr int CL  = (R >= 8) ? TM : (TM * R / 8);  // m per thread per rep
  constexpr int REP = (R == 16) ? 2 : 1;

  const int L = SEQ - j;
  const int tid = threadIdx.x;
  const int g = tid >> 3, s = tid & 7;

  // per-thread LDS histogram bases (slot = g*8 + bin)
  float* bmx = BinMax + g * 8;
  float* bmn = BinMin + g * 8;

  // weights: 8 out-ch x 9 taps -> 4 half2 + 1 f32 tail per channel (40 regs)
  h2_t Wp[8][4];
  float Wt[8];
  {
    const float* wp = W + (size_t)((DI * 2 + j) * 256 + g * 8) * 9;
#pragma unroll
    for (int k = 0; k < 8; ++k) {
#pragma unroll
      for (int t = 0; t < 4; ++t)
        Wp[k][t] = __builtin_amdgcn_cvt_pkrtz(wp[k * 9 + 2 * t], wp[k * 9 + 2 * t + 1]);
      Wt[k] = wp[k * 9 + 8];
    }
  }
  const float* base[CPER];
  {
    const int* ip = I + ((DI * 2 + j) * NG + g) * CPER;
#pragma unroll
    for (int i = 0; i < CPER; ++i) base[i] = Xs + ip[i] * CS;
  }

  // zero the LDS histograms (covered by the staging __syncthreads)
  BinMax[tid] = 0.f;
  BinMin[tid] = 0.f;

  for (int n = 0; n < NR; ++n) {
    const int cidx = chunk + 16 * n;
    const int rc = cidx & (RC - 1);
    const int mc = cidx / RC;
    const int r0 = rc * R;
    const int m0 = mc * TM;

    if (NR > 1 && n) __syncthreads();

    // ---- stage 12-channel tile into LDS, zero-padded; guards hoisted ----
    {
      const float* xb0 = X + (size_t)b * CIN * SEQ;
      if (j == 0) {
        for (int f = tid; f < R * SR; f += 256) {
          int rr = f & (R - 1), mm = f >> rb, mp = m0 + mm - 4;
          int pos = r0 + rr + mp * d;
          bool ok = (mp >= 0) && (pos < L);
          int lo = rr * SR + mm;
          const float* xp = xb0 + pos;
#pragma unroll
          for (int ch = 0; ch < CIN; ++ch) {
            Xs[ch * CS + lo] = ok ? xp[0] : 0.f;
            xp += SEQ;
          }
        }
      } else {
        for (int f = tid; f < R * SR; f += 256) {
          int rr = f & (R - 1), mm = f >> rb, mp = m0 + mm - 4;
          int pos = r0 + rr + mp * d;
          bool ok = (mp >= 0) && (pos < L);
          int lo = rr * SR + mm;
          const float* xp = xb0 + pos;
#pragma unroll
          for (int ch = 0; ch < CIN; ++ch) {
            Xs[ch * CS + lo] = ok ? (xp[1] - xp[0]) : 0.f;
            xp += SEQ;
          }
        }
      }
    }
    __syncthreads();

    // ---- compute: sliding window, dot2 conv, mantissa-tag binning ----
#pragma unroll
    for (int rep = 0; rep < REP; ++rep) {
      int rr = (R == 16) ? (s + (rep << 3)) : (s & (R - 1));
      int mst = (R >= 8) ? 0 : ((s >> rb) * CL);
      int rowoff = rr * SR + mst;

      auto ldsum = [&](int idx) {
        float4 r = *reinterpret_cast<const float4*>(base[0] + idx);
#pragma unroll
        for (int i = 1; i < CPER; ++i) {
          float4 t = *reinterpret_cast<const float4*>(base[i] + idx);
          r.x += t.x; r.y += t.y; r.z += t.z; r.w += t.w;
        }
        return r;
      };

      float4 w0 = ldsum(rowoff);
      float4 w1 = ldsum(rowoff + 4);
#pragma unroll 2
      for (int st = 0; st < CL; st += 4) {
        float4 w2 = ldsum(rowoff + st + 8);
        float xv[12] = {w0.x, w0.y, w0.z, w0.w,
                        w1.x, w1.y, w1.z, w1.w,
                        w2.x, w2.y, w2.z, w2.w};
        // even- and odd-aligned f16 pair windows covering xv[0..11]
        h2_t E[5], O[5];
#pragma unroll
        for (int i = 0; i < 5; ++i) {
          E[i] = __builtin_amdgcn_cvt_pkrtz(xv[2 * i],     xv[2 * i + 1]);
          O[i] = __builtin_amdgcn_cvt_pkrtz(xv[2 * i + 1], xv[2 * i + 2]);
        }
#pragma unroll
        for (int p = 0; p < 4; ++p) {
          const h2_t* P = (p & 1) ? (O + (p >> 1)) : (E + (p >> 1));
          float tail = xv[8 + p];
          // conv + mantissa-tag in one pass: zp[k] = (bits(z)&~7)|k
          float zp[8];
#pragma unroll
          for (int k = 0; k < 8; ++k) {
            float acc = Wt[k] * tail;
            acc = __builtin_amdgcn_fdot2(Wp[k][3], P[3], acc, false);
            acc = __builtin_amdgcn_fdot2(Wp[k][2], P[2], acc, false);
            acc = __builtin_amdgcn_fdot2(Wp[k][1], P[1], acc, false);
            acc = __builtin_amdgcn_fdot2(Wp[k][0], P[0], acc, false);
            zp[k] = __uint_as_float((__float_as_uint(acc) & 0xFFFFFFF8u) | (unsigned)k);
          }
          float mxp = fmaxf(fmaxf(fmaxf(zp[0], zp[1]), fmaxf(zp[2], zp[3])),
                            fmaxf(fmaxf(zp[4], zp[5]), fmaxf(zp[6], zp[7])));
          float mnp = fminf(fminf(fminf(zp[0], zp[1]), fminf(zp[2], zp[3])),
                            fminf(fminf(zp[4], zp[5]), fminf(zp[6], zp[7])));
          unsigned mxb = __float_as_uint(mxp);
          unsigned mnb = __float_as_uint(mnp);
          atomicAdd(bmx + (mxb & 7u), __uint_as_float(mxb & 0xFFFFFFF8u));
          atomicAdd(bmn + (mnb & 7u), 1.0f);
        }
        w0 = w1; w1 = w2;
      }
    }
  }

  // ---- flush LDS histograms: thread tid owns slot (g=tid>>3, k=tid&7) ----
  __syncthreads();
  {
    int k = tid & 7;
    int cbase = (DI * 2 + j) * 64;
    atomicAdd(out + ((size_t)b * OUTCH + cbase + g) * 8 + k,      BinMax[tid]);
    atomicAdd(out + ((size_t)b * OUTCH + cbase + 32 + g) * 8 + k, BinMin[tid]);
  }
}

__global__ __launch_bounds__(256, 4) void hydra_fused(
    const float* __restrict__ X, const float* __restrict__ W,
    const int* __restrict__ I, float* __restrict__ out) {
  __shared__ float Xs[XS_FLOATS];
  __shared__ float BinMax[256];
  __shared__ float BinMin[256];
  int u = blockIdx.x;
  int dj = u % 20;            // consecutive blocks interleave (di,j)
  int rest = u / 20;
  int b = rest & 31;
  int chunk = rest >> 5;
  int j = dj & 1;
  switch (dj >> 1) {
    case 0: hydra_body<0>(X, W, I, out, Xs, BinMax, BinMin, j, b, chunk); break;
    case 1: hydra_body<1>(X, W, I, out, Xs, BinMax, BinMin, j, b, chunk); break;
    case 2: hydra_body<2>(X, W, I, out, Xs, BinMax, BinMin, j, b, chunk); break;
    case 3: hydra_body<3>(X, W, I, out, Xs, BinMax, BinMin, j, b, chunk); break;
    case 4: hydra_body<4>(X, W, I, out, Xs, BinMax, BinMin, j, b, chunk); break;
    case 5: hydra_body<5>(X, W, I, out, Xs, BinMax, BinMin, j, b, chunk); break;
    case 6: hydra_body<6>(X, W, I, out, Xs, BinMax, BinMin, j, b, chunk); break;
    case 7: hydra_body<7>(X, W, I, out, Xs, BinMax, BinMin, j, b, chunk); break;
    case 8: hydra_body<8>(X, W, I, out, Xs, BinMax, BinMin, j, b, chunk); break;
    case 9: hydra_body<9>(X, W, I, out, Xs, BinMax, BinMin, j, b, chunk); break;
  }
}

__global__ void hydra_relu(float* __restrict__ out, int n) {
  int i = blockIdx.x * 256 + threadIdx.x;
  if (i < n) out[i] = fmaxf(out[i], 0.f);
}

extern "C" void kernel_launch(void* const* d_in, const int* in_sizes, int n_in,
                              void* d_out, int out_size, void* d_ws, size_t ws_size,
                              hipStream_t stream) {
  const float* X = (const float*)d_in[0];
  const float* W = (const float*)d_in[1];
  const int*   I = (const int*)d_in[2];
  float* out = (float*)d_out;

  (void)hipMemsetAsync(d_out, 0, (size_t)out_size * sizeof(float), stream);
  hydra_fused<<<GRID, 256, 0, stream>>>(X, W, I, out);
  hydra_relu<<<(out_size + 255) / 256, 256, 0, stream>>>(out, out_size);
}

// Round 9
// 686.735 us; speedup vs baseline: 2.7646x; 2.7646x over previous
//
#include <hip/hip_runtime.h>

// HydraBackbonePlus: 10 dilations x {X, diffX} x 32 groups, 9-tap grouped dilated
// conv (8 out-ch per group), per-position argmax/argmin over 8 channels,
// histogram-reduced to (32, 1280, 8) with relu.
//
// R9 vs R8 (LDS float atomicAdd = CAS loop + 8-way same-slot contention ->
// 4x regression): keep mantissa-tag binning, commit via contention-free
// per-THREAD LDS slots with plain ds_read/add/ds_write (no atomic):
//   Smx[bin*256 + tid] -- 64 lanes span 32 banks 2-way (free, m136).
// cmx: tag(8 v_and_or) + trees(14) + addr(2) + add(1) + 2 DS  (~25V+2DS)
// cmn: register addc on tagged-bit equality (16) -- also kills tie dup.
// Flush: thread (g,s) sums bin=s over its 8 member threads + 1 global atomic;
// cmn via R7 butterfly. Tagged val added un-stripped (<=8 ulp, noise).

typedef __fp16 h2_t __attribute__((ext_vector_type(2)));

#define NB    32
#define CIN   12
#define SEQ   8192
#define NG    32
#define CPER  6
#define OUTCH 1280
#define XS_FLOATS 7728   // 12 * 644 = max over DI of CIN*CS
#define GRID  10240      // 20 (di,j) * 32 b * 16 chunks

template <int DI>
__device__ __forceinline__ void hydra_body(
    const float* __restrict__ X, const float* __restrict__ W,
    const int* __restrict__ I, float* __restrict__ out,
    float* Xs, float* Smx, int j, int b, int chunk) {

  constexpr int d   = 1 << DI;
  constexpr int R   = (d < 16) ? d : 16;       // residues per tile row-set
  constexpr int rb  = (DI < 4) ? DI : 4;       // log2(R)
  constexpr int Mm  = SEQ / d;                 // m-extent of a residue
  constexpr int TMc = 512 / R;
  constexpr int TM  = (TMc < Mm) ? TMc : Mm;   // m per tile (DI=9 -> 16)
  constexpr int MC  = Mm / TM;
  constexpr int RC  = d / R;
  constexpr int NR  = (RC * MC) / 16;          // chunks per block: 1 (DI<9), 2 (DI=9)
  constexpr int SR  = TM + 8;                  // row stride (exact halo)
  constexpr int CS  = R * SR + 4;              // channel stride
  constexpr int CL  = (R >= 8) ? TM : (TM * R / 8);  // m per thread per rep
  constexpr int REP = (R == 16) ? 2 : 1;

  const int L = SEQ - j;
  const int tid = threadIdx.x;
  const int g = tid >> 3, s = tid & 7;

  // weights: 8 out-ch x 9 taps -> 4 half2 + 1 f32 tail per channel (40 regs)
  h2_t Wp[8][4];
  float Wt[8];
  {
    const float* wp = W + (size_t)((DI * 2 + j) * 256 + g * 8) * 9;
#pragma unroll
    for (int k = 0; k < 8; ++k) {
#pragma unroll
      for (int t = 0; t < 4; ++t)
        Wp[k][t] = __builtin_amdgcn_cvt_pkrtz(wp[k * 9 + 2 * t], wp[k * 9 + 2 * t + 1]);
      Wt[k] = wp[k * 9 + 8];
    }
  }
  const float* base[CPER];
  {
    const int* ip = I + ((DI * 2 + j) * NG + g) * CPER;
#pragma unroll
    for (int i = 0; i < CPER; ++i) base[i] = Xs + ip[i] * CS;
  }

  // zero the per-thread cmx slots (covered by the staging __syncthreads)
#pragma unroll
  for (int k = 0; k < 8; ++k) Smx[k * 256 + tid] = 0.f;

  int cmni[8] = {0,0,0,0,0,0,0,0};

  for (int n = 0; n < NR; ++n) {
    const int cidx = chunk + 16 * n;
    const int rc = cidx & (RC - 1);
    const int mc = cidx / RC;
    const int r0 = rc * R;
    const int m0 = mc * TM;

    if (NR > 1 && n) __syncthreads();

    // ---- stage 12-channel tile into LDS, zero-padded; guards hoisted ----
    {
      const float* xb0 = X + (size_t)b * CIN * SEQ;
      if (j == 0) {
        for (int f = tid; f < R * SR; f += 256) {
          int rr = f & (R - 1), mm = f >> rb, mp = m0 + mm - 4;
          int pos = r0 + rr + mp * d;
          bool ok = (mp >= 0) && (pos < L);
          int lo = rr * SR + mm;
          const float* xp = xb0 + pos;
#pragma unroll
          for (int ch = 0; ch < CIN; ++ch) {
            Xs[ch * CS + lo] = ok ? xp[0] : 0.f;
            xp += SEQ;
          }
        }
      } else {
        for (int f = tid; f < R * SR; f += 256) {
          int rr = f & (R - 1), mm = f >> rb, mp = m0 + mm - 4;
          int pos = r0 + rr + mp * d;
          bool ok = (mp >= 0) && (pos < L);
          int lo = rr * SR + mm;
          const float* xp = xb0 + pos;
#pragma unroll
          for (int ch = 0; ch < CIN; ++ch) {
            Xs[ch * CS + lo] = ok ? (xp[1] - xp[0]) : 0.f;
            xp += SEQ;
          }
        }
      }
    }
    __syncthreads();

    // ---- compute: sliding window, dot2 conv, mantissa-tag binning ----
#pragma unroll
    for (int rep = 0; rep < REP; ++rep) {
      int rr = (R == 16) ? (s + (rep << 3)) : (s & (R - 1));
      int mst = (R >= 8) ? 0 : ((s >> rb) * CL);
      int rowoff = rr * SR + mst;

      auto ldsum = [&](int idx) {
        float4 r = *reinterpret_cast<const float4*>(base[0] + idx);
#pragma unroll
        for (int i = 1; i < CPER; ++i) {
          float4 t = *reinterpret_cast<const float4*>(base[i] + idx);
          r.x += t.x; r.y += t.y; r.z += t.z; r.w += t.w;
        }
        return r;
      };

      float4 w0 = ldsum(rowoff);
      float4 w1 = ldsum(rowoff + 4);
#pragma unroll 2
      for (int st = 0; st < CL; st += 4) {
        float4 w2 = ldsum(rowoff + st + 8);
        float xv[12] = {w0.x, w0.y, w0.z, w0.w,
                        w1.x, w1.y, w1.z, w1.w,
                        w2.x, w2.y, w2.z, w2.w};
        // even- and odd-aligned f16 pair windows covering xv[0..11]
        h2_t E[5], O[5];
#pragma unroll
        for (int i = 0; i < 5; ++i) {
          E[i] = __builtin_amdgcn_cvt_pkrtz(xv[2 * i],     xv[2 * i + 1]);
          O[i] = __builtin_amdgcn_cvt_pkrtz(xv[2 * i + 1], xv[2 * i + 2]);
        }
#pragma unroll
        for (int p = 0; p < 4; ++p) {
          const h2_t* P = (p & 1) ? (O + (p >> 1)) : (E + (p >> 1));
          float tail = xv[8 + p];
          // conv + mantissa-tag: zp[k] = (bits(z) & ~7) | k  (v_and_or_b32)
          float zp[8];
#pragma unroll
          for (int k = 0; k < 8; ++k) {
            float acc = Wt[k] * tail;
            acc = __builtin_amdgcn_fdot2(Wp[k][3], P[3], acc, false);
            acc = __builtin_amdgcn_fdot2(Wp[k][2], P[2], acc, false);
            acc = __builtin_amdgcn_fdot2(Wp[k][1], P[1], acc, false);
            acc = __builtin_amdgcn_fdot2(Wp[k][0], P[0], acc, false);
            zp[k] = __uint_as_float((__float_as_uint(acc) & 0xFFFFFFF8u) | (unsigned)k);
          }
          float mxp = fmaxf(fmaxf(fmaxf(zp[0], zp[1]), fmaxf(zp[2], zp[3])),
                            fmaxf(fmaxf(zp[4], zp[5]), fmaxf(zp[6], zp[7])));
          float mnp = fminf(fminf(fminf(zp[0], zp[1]), fminf(zp[2], zp[3])),
                            fminf(fminf(zp[4], zp[5]), fminf(zp[6], zp[7])));
          // cmx: contention-free per-thread LDS slot RMW (no atomic)
          unsigned mxb = __float_as_uint(mxp);
          float* slot = Smx + ((mxb & 7u) << 8) + tid;
          *slot += mxp;   // tagged value: <=8 ulp bias, negligible
          // cmn: register accumulate on exact tagged-bit equality
          unsigned mnb = __float_as_uint(mnp);
#pragma unroll
          for (int k = 0; k < 8; ++k)
            cmni[k] += (__float_as_uint(zp[k]) == mnb);
        }
        w0 = w1; w1 = w2;
      }
    }
  }

  __syncthreads();

  // ---- flush cmx: thread (g,s) sums bin=s over its 8 member threads ----
  {
    float sum = 0.f;
#pragma unroll
    for (int s2 = 0; s2 < 8; ++s2) sum += Smx[(s << 8) + (g << 3) + s2];
    int cbase = (DI * 2 + j) * 64;
    atomicAdd(out + ((size_t)b * OUTCH + cbase + g) * 8 + s, sum);

    // ---- flush cmn: butterfly over the 8 s-lanes, lane s commits bin s ----
#pragma unroll
    for (int k = 0; k < 8; ++k) {
#pragma unroll
      for (int off = 1; off < 8; off <<= 1)
        cmni[k] += __shfl_xor(cmni[k], off);
    }
    int vn = cmni[0];
#pragma unroll
    for (int k = 1; k < 8; ++k) vn = (s == k) ? cmni[k] : vn;
    atomicAdd(out + ((size_t)b * OUTCH + cbase + 32 + g) * 8 + s, (float)vn);
  }
}

__global__ __launch_bounds__(256, 4) void hydra_fused(
    const float* __restrict__ X, const float* __restrict__ W,
    const int* __restrict__ I, float* __restrict__ out) {
  __shared__ float Xs[XS_FLOATS];
  __shared__ float Smx[2048];   // 8 bins x 256 threads
  int u = blockIdx.x;
  int dj = u % 20;            // consecutive blocks interleave (di,j)
  int rest = u / 20;
  int b = rest & 31;
  int chunk = rest >> 5;
  int j = dj & 1;
  switch (dj >> 1) {
    case 0: hydra_body<0>(X, W, I, out, Xs, Smx, j, b, chunk); break;
    case 1: hydra_body<1>(X, W, I, out, Xs, Smx, j, b, chunk); break;
    case 2: hydra_body<2>(X, W, I, out, Xs, Smx, j, b, chunk); break;
    case 3: hydra_body<3>(X, W, I, out, Xs, Smx, j, b, chunk); break;
    case 4: hydra_body<4>(X, W, I, out, Xs, Smx, j, b, chunk); break;
    case 5: hydra_body<5>(X, W, I, out, Xs, Smx, j, b, chunk); break;
    case 6: hydra_body<6>(X, W, I, out, Xs, Smx, j, b, chunk); break;
    case 7: hydra_body<7>(X, W, I, out, Xs, Smx, j, b, chunk); break;
    case 8: hydra_body<8>(X, W, I, out, Xs, Smx, j, b, chunk); break;
    case 9: hydra_body<9>(X, W, I, out, Xs, Smx, j, b, chunk); break;
  }
}

__global__ void hydra_relu(float* __restrict__ out, int n) {
  int i = blockIdx.x * 256 + threadIdx.x;
  if (i < n) out[i] = fmaxf(out[i], 0.f);
}

extern "C" void kernel_launch(void* const* d_in, const int* in_sizes, int n_in,
                              void* d_out, int out_size, void* d_ws, size_t ws_size,
                              hipStream_t stream) {
  const float* X = (const float*)d_in[0];
  const float* W = (const float*)d_in[1];
  const int*   I = (const int*)d_in[2];
  float* out = (float*)d_out;

  (void)hipMemsetAsync(d_out, 0, (size_t)out_size * sizeof(float), stream);
  hydra_fused<<<GRID, 256, 0, stream>>>(X, W, I, out);
  hydra_relu<<<(out_size + 255) / 256, 256, 0, stream>>>(out, out_size);
}

// Round 10
// 428.299 us; speedup vs baseline: 4.4327x; 1.6034x over previous
//
#include <hip/hip_runtime.h>

// HydraBackbonePlus: 10 dilations x {X, diffX} x 32 groups, 9-tap grouped dilated
// conv (8 out-ch per group), per-position argmax/argmin over 8 channels,
// histogram-reduced to (32, 1280, 8) with relu.
//
// R10 vs R9 (LDS scatter was right; unroll-2 live-range bloat spilled 86
// dwords/thread to scratch -> 1.3GB traffic):
//  - #pragma unroll 1 on the st-loop (p-loop still fully unrolled; E/O static)
//  - cmn as packed u8x8 in one u64: commit = lshl_b64 + add64 (~5 VALU, was 16)
//  - __launch_bounds__(256,3): ~168-reg budget, no spill cliff
// cmx commit: mantissa-tag bin -> per-THREAD LDS slot Smx[bin*256+tid] plain
// RMW (no atomic, no cross-thread contention; 2-way bank alias is free).

typedef __fp16 h2_t __attribute__((ext_vector_type(2)));

#define NB    32
#define CIN   12
#define SEQ   8192
#define NG    32
#define CPER  6
#define OUTCH 1280
#define XS_FLOATS 7728   // 12 * 644 = max over DI of CIN*CS
#define GRID  10240      // 20 (di,j) * 32 b * 16 chunks

template <int DI>
__device__ __forceinline__ void hydra_body(
    const float* __restrict__ X, const float* __restrict__ W,
    const int* __restrict__ I, float* __restrict__ out,
    float* Xs, float* Smx, int j, int b, int chunk) {

  constexpr int d   = 1 << DI;
  constexpr int R   = (d < 16) ? d : 16;       // residues per tile row-set
  constexpr int rb  = (DI < 4) ? DI : 4;       // log2(R)
  constexpr int Mm  = SEQ / d;                 // m-extent of a residue
  constexpr int TMc = 512 / R;
  constexpr int TM  = (TMc < Mm) ? TMc : Mm;   // m per tile (DI=9 -> 16)
  constexpr int MC  = Mm / TM;
  constexpr int RC  = d / R;
  constexpr int NR  = (RC * MC) / 16;          // chunks per block: 1 (DI<9), 2 (DI=9)
  constexpr int SR  = TM + 8;                  // row stride (exact halo)
  constexpr int CS  = R * SR + 4;              // channel stride
  constexpr int CL  = (R >= 8) ? TM : (TM * R / 8);  // m per thread per rep
  constexpr int REP = (R == 16) ? 2 : 1;

  const int L = SEQ - j;
  const int tid = threadIdx.x;
  const int g = tid >> 3, s = tid & 7;

  // weights: 8 out-ch x 9 taps -> 4 half2 + 1 f32 tail per channel (40 regs)
  h2_t Wp[8][4];
  float Wt[8];
  {
    const float* wp = W + (size_t)((DI * 2 + j) * 256 + g * 8) * 9;
#pragma unroll
    for (int k = 0; k < 8; ++k) {
#pragma unroll
      for (int t = 0; t < 4; ++t)
        Wp[k][t] = __builtin_amdgcn_cvt_pkrtz(wp[k * 9 + 2 * t], wp[k * 9 + 2 * t + 1]);
      Wt[k] = wp[k * 9 + 8];
    }
  }
  const float* base[CPER];
  {
    const int* ip = I + ((DI * 2 + j) * NG + g) * CPER;
#pragma unroll
    for (int i = 0; i < CPER; ++i) base[i] = Xs + ip[i] * CS;
  }

  // zero the per-thread cmx slots (covered by the staging __syncthreads)
#pragma unroll
  for (int k = 0; k < 8; ++k) Smx[k * 256 + tid] = 0.f;

  // cmn: 8 bins as packed u8 lanes of one u64 (counts <= 64/thread)
  unsigned long long cmnp = 0ull;

  for (int n = 0; n < NR; ++n) {
    const int cidx = chunk + 16 * n;
    const int rc = cidx & (RC - 1);
    const int mc = cidx / RC;
    const int r0 = rc * R;
    const int m0 = mc * TM;

    if (NR > 1 && n) __syncthreads();

    // ---- stage 12-channel tile into LDS, zero-padded; guards hoisted ----
    {
      const float* xb0 = X + (size_t)b * CIN * SEQ;
      if (j == 0) {
        for (int f = tid; f < R * SR; f += 256) {
          int rr = f & (R - 1), mm = f >> rb, mp = m0 + mm - 4;
          int pos = r0 + rr + mp * d;
          bool ok = (mp >= 0) && (pos < L);
          int lo = rr * SR + mm;
          const float* xp = xb0 + pos;
#pragma unroll
          for (int ch = 0; ch < CIN; ++ch) {
            Xs[ch * CS + lo] = ok ? xp[0] : 0.f;
            xp += SEQ;
          }
        }
      } else {
        for (int f = tid; f < R * SR; f += 256) {
          int rr = f & (R - 1), mm = f >> rb, mp = m0 + mm - 4;
          int pos = r0 + rr + mp * d;
          bool ok = (mp >= 0) && (pos < L);
          int lo = rr * SR + mm;
          const float* xp = xb0 + pos;
#pragma unroll
          for (int ch = 0; ch < CIN; ++ch) {
            Xs[ch * CS + lo] = ok ? (xp[1] - xp[0]) : 0.f;
            xp += SEQ;
          }
        }
      }
    }
    __syncthreads();

    // ---- compute: sliding window, dot2 conv, mantissa-tag binning ----
#pragma unroll
    for (int rep = 0; rep < REP; ++rep) {
      int rr = (R == 16) ? (s + (rep << 3)) : (s & (R - 1));
      int mst = (R >= 8) ? 0 : ((s >> rb) * CL);
      int rowoff = rr * SR + mst;

      auto ldsum = [&](int idx) {
        float4 r = *reinterpret_cast<const float4*>(base[0] + idx);
#pragma unroll
        for (int i = 1; i < CPER; ++i) {
          float4 t = *reinterpret_cast<const float4*>(base[i] + idx);
          r.x += t.x; r.y += t.y; r.z += t.z; r.w += t.w;
        }
        return r;
      };

      float4 w0 = ldsum(rowoff);
      float4 w1 = ldsum(rowoff + 4);
#pragma unroll 1
      for (int st = 0; st < CL; st += 4) {
        float4 w2 = ldsum(rowoff + st + 8);
        float xv[12] = {w0.x, w0.y, w0.z, w0.w,
                        w1.x, w1.y, w1.z, w1.w,
                        w2.x, w2.y, w2.z, w2.w};
        // even- and odd-aligned f16 pair windows covering xv[0..11]
        h2_t E[5], O[5];
#pragma unroll
        for (int i = 0; i < 5; ++i) {
          E[i] = __builtin_amdgcn_cvt_pkrtz(xv[2 * i],     xv[2 * i + 1]);
          O[i] = __builtin_amdgcn_cvt_pkrtz(xv[2 * i + 1], xv[2 * i + 2]);
        }
#pragma unroll
        for (int p = 0; p < 4; ++p) {
          const h2_t* P = (p & 1) ? (O + (p >> 1)) : (E + (p >> 1));
          float tail = xv[8 + p];
          // conv + mantissa-tag: zp[k] = (bits(z) & ~7) | k  (v_and_or_b32)
          float zp[8];
#pragma unroll
          for (int k = 0; k < 8; ++k) {
            float acc = Wt[k] * tail;
            acc = __builtin_amdgcn_fdot2(Wp[k][3], P[3], acc, false);
            acc = __builtin_amdgcn_fdot2(Wp[k][2], P[2], acc, false);
            acc = __builtin_amdgcn_fdot2(Wp[k][1], P[1], acc, false);
            acc = __builtin_amdgcn_fdot2(Wp[k][0], P[0], acc, false);
            zp[k] = __uint_as_float((__float_as_uint(acc) & 0xFFFFFFF8u) | (unsigned)k);
          }
          float mxp = fmaxf(fmaxf(fmaxf(zp[0], zp[1]), fmaxf(zp[2], zp[3])),
                            fmaxf(fmaxf(zp[4], zp[5]), fmaxf(zp[6], zp[7])));
          float mnp = fminf(fminf(fminf(zp[0], zp[1]), fminf(zp[2], zp[3])),
                            fminf(fminf(zp[4], zp[5]), fminf(zp[6], zp[7])));
          // cmx: contention-free per-thread LDS slot RMW (no atomic)
          unsigned mxb = __float_as_uint(mxp);
          Smx[((mxb & 7u) << 8) + tid] += mxp;   // tagged val: <=8 ulp bias
          // cmn: packed-byte histogram in a u64 register
          unsigned mnb = __float_as_uint(mnp);
          cmnp += 1ull << ((mnb & 7u) << 3);
        }
        w0 = w1; w1 = w2;
      }
    }
  }

  __syncthreads();

  // ---- flush ----
  {
    int cbase = (DI * 2 + j) * 64;
    // cmx: thread (g,s) sums bin=s over its 8 member threads
    float sum = 0.f;
#pragma unroll
    for (int s2 = 0; s2 < 8; ++s2) sum += Smx[(s << 8) + (g << 3) + s2];
    atomicAdd(out + ((size_t)b * OUTCH + cbase + g) * 8 + s, sum);

    // cmn: unpack bytes, butterfly over the 8 s-lanes, lane s commits bin s
    int cnts[8];
#pragma unroll
    for (int k = 0; k < 8; ++k) cnts[k] = (int)((cmnp >> (k * 8)) & 0xFFull);
#pragma unroll
    for (int k = 0; k < 8; ++k) {
#pragma unroll
      for (int off = 1; off < 8; off <<= 1)
        cnts[k] += __shfl_xor(cnts[k], off);
    }
    int vn = cnts[0];
#pragma unroll
    for (int k = 1; k < 8; ++k) vn = (s == k) ? cnts[k] : vn;
    atomicAdd(out + ((size_t)b * OUTCH + cbase + 32 + g) * 8 + s, (float)vn);
  }
}

__global__ __launch_bounds__(256, 3) void hydra_fused(
    const float* __restrict__ X, const float* __restrict__ W,
    const int* __restrict__ I, float* __restrict__ out) {
  __shared__ float Xs[XS_FLOATS];
  __shared__ float Smx[2048];   // 8 bins x 256 threads
  int u = blockIdx.x;
  int dj = u % 20;            // consecutive blocks interleave (di,j)
  int rest = u / 20;
  int b = rest & 31;
  int chunk = rest >> 5;
  int j = dj & 1;
  switch (dj >> 1) {
    case 0: hydra_body<0>(X, W, I, out, Xs, Smx, j, b, chunk); break;
    case 1: hydra_body<1>(X, W, I, out, Xs, Smx, j, b, chunk); break;
    case 2: hydra_body<2>(X, W, I, out, Xs, Smx, j, b, chunk); break;
    case 3: hydra_body<3>(X, W, I, out, Xs, Smx, j, b, chunk); break;
    case 4: hydra_body<4>(X, W, I, out, Xs, Smx, j, b, chunk); break;
    case 5: hydra_body<5>(X, W, I, out, Xs, Smx, j, b, chunk); break;
    case 6: hydra_body<6>(X, W, I, out, Xs, Smx, j, b, chunk); break;
    case 7: hydra_body<7>(X, W, I, out, Xs, Smx, j, b, chunk); break;
    case 8: hydra_body<8>(X, W, I, out, Xs, Smx, j, b, chunk); break;
    case 9: hydra_body<9>(X, W, I, out, Xs, Smx, j, b, chunk); break;
  }
}

__global__ void hydra_relu(float* __restrict__ out, int n) {
  int i = blockIdx.x * 256 + threadIdx.x;
  if (i < n) out[i] = fmaxf(out[i], 0.f);
}

extern "C" void kernel_launch(void* const* d_in, const int* in_sizes, int n_in,
                              void* d_out, int out_size, void* d_ws, size_t ws_size,
                              hipStream_t stream) {
  const float* X = (const float*)d_in[0];
  const float* W = (const float*)d_in[1];
  const int*   I = (const int*)d_in[2];
  float* out = (float*)d_out;

  (void)hipMemsetAsync(d_out, 0, (size_t)out_size * sizeof(float), stream);
  hydra_fused<<<GRID, 256, 0, stream>>>(X, W, I, out);
  hydra_relu<<<(out_size + 255) / 256, 256, 0, stream>>>(out, out_size);
}